// Round 17
// baseline (27.922 us; speedup 1.0000x reference)
//
#include <hip/hip_runtime.h>

// GSplat renderer as a bf16 MFMA GEMM — R17 = R16 + MEASUREMENT:
// gs_mfma is launched TWICE (idempotent: partials fully overwritten with
// identical values; deterministic). dTotal vs R16 = dur(gs_mfma) + ~1us
// launch gap. Decides whether remaining slack is in gs_mfma (attack kernel
// internals next) or in plumbing/finalize/fixed-floor (attack reduction path).
// Everything else byte-identical to R16 (18.97us, absmax 0.0039).

constexpr int PIX = 65536;
constexpr int KCH = 256;     // K-chunk (gaussians per block)
constexpr int KSPLIT = 8;
constexpr int MT = 64;
constexpr int NT = 64;
constexpr float COORD_STEP = 2.0f / 255.0f;

typedef __attribute__((ext_vector_type(8))) short short8;
typedef __attribute__((ext_vector_type(4))) float f32x4;

__device__ __forceinline__ unsigned cvt_pk_bf16(float lo, float hi) {
  unsigned r;
  asm("v_cvt_pk_bf16_f32 %0, %1, %2" : "=v"(r) : "v"(lo), "v"(hi));
  return r;
}

__global__ __launch_bounds__(256) void gs_mfma(
    const float* __restrict__ means, const float* __restrict__ scales,
    const float* __restrict__ opac, const float* __restrict__ colors,
    float* __restrict__ partials) {
  __shared__ unsigned short A_l[MT * KCH];  // bf16 bits, swizzled rows
  __shared__ unsigned short B_l[NT * KCH];  // bf16 bits (n-major), swizzled
  __shared__ float pxL[KCH], pyL[KCH], kKL[KCH], colL[KCH];

  const int t = threadIdx.x;
  const int mt = blockIdx.x;          // 0..15: c = mt>>2, rowband (mt&3)*64
  const int nt = blockIdx.y;          // 0..3
  const int kp = blockIdx.z;          // 0..7
  const int c = mt >> 2;
  const int row0 = (mt & 3) * MT;
  const int col0 = nt * NT;

  // --- per-gaussian params for this K-chunk (1 per thread) ---
  {
    int n = kp * KCH + t;
    float mx = means[3 * n], my = means[3 * n + 1], mz = means[3 * n + 2];
    float scl = fmaxf((scales[3 * n] + scales[3 * n + 1] + scales[3 * n + 2]) * (1.0f / 3.0f), 1e-4f);
    float op = opac[n];
    float rzs = 1.0f / (fabsf(mz) + 1.0f);
    float sigma = fminf(fmaxf(scl * rzs, 0.02f), 0.5f);
    float inv_s = 1.0f / sigma;
    pxL[t] = tanhf(mx * rzs);
    pyL[t] = tanhf(my * rzs);
    kKL[t] = -0.72134752044f * inv_s * inv_s;  // -0.5/ln2 * inv_s^2
    colL[t] = (c < 3) ? op * colors[3 * n + c] : op;
  }
  __syncthreads();

  // --- stage A (ey*col) and Bt (ex) tiles, bf16, swizzled ---
  {
    const int kq = (t & 63) << 2;       // element k base
    const int mq = (t >> 6) << 4;       // local row/col base
    const int kbyte = (t & 63) << 3;    // byte offset of the 4-bf16 group
    float py0 = pyL[kq + 0], py1 = pyL[kq + 1], py2 = pyL[kq + 2], py3 = pyL[kq + 3];
    float px0 = pxL[kq + 0], px1 = pxL[kq + 1], px2 = pxL[kq + 2], px3 = pxL[kq + 3];
    float K0 = kKL[kq + 0], K1 = kKL[kq + 1], K2 = kKL[kq + 2], K3 = kKL[kq + 3];
    float c0 = colL[kq + 0], c1 = colL[kq + 1], c2 = colL[kq + 2], c3 = colL[kq + 3];
#pragma unroll 4
    for (int j = 0; j < 16; ++j) {
      int m = mq + j;
      float cr = -1.0f + COORD_STEP * (float)(row0 + m);
      float d0 = cr - py0, d1 = cr - py1, d2 = cr - py2, d3 = cr - py3;
      float e0 = exp2f(K0 * d0 * d0) * c0;
      float e1 = exp2f(K1 * d1 * d1) * c1;
      float e2 = exp2f(K2 * d2 * d2) * c2;
      float e3 = exp2f(K3 * d3 * d3) * c3;
      uint2 pa;
      pa.x = cvt_pk_bf16(e0, e1);
      pa.y = cvt_pk_bf16(e2, e3);
      *(uint2*)((char*)A_l + ((m * 512 + kbyte) ^ ((m & 7) << 4))) = pa;
      float cc = -1.0f + COORD_STEP * (float)(col0 + m);
      float f0 = cc - px0, f1 = cc - px1, f2 = cc - px2, f3 = cc - px3;
      float g0 = exp2f(K0 * f0 * f0);
      float g1 = exp2f(K1 * f1 * f1);
      float g2 = exp2f(K2 * f2 * f2);
      float g3 = exp2f(K3 * f3 * f3);
      uint2 pb;
      pb.x = cvt_pk_bf16(g0, g1);
      pb.y = cvt_pk_bf16(g2, g3);
      *(uint2*)((char*)B_l + ((m * 512 + kbyte) ^ ((m & 7) << 4))) = pb;
    }
  }
  __syncthreads();

  // --- MFMA phase: wave w -> rows [w*16, +16), all 64 cols ---
  const int w = t >> 6;
  const int lr = t & 15;
  const int lg = (t >> 4) & 3;

  f32x4 acc0 = {0.f, 0.f, 0.f, 0.f};
  f32x4 acc1 = acc0, acc2 = acc0, acc3 = acc0;

  const int ra = w * 16 + lr;
  const unsigned offA = (unsigned)(ra * 512 + lg * 16);
  const unsigned swA = (unsigned)((ra & 7) << 4);
  const int nb0 = 0 * 16 + lr, nb1 = 1 * 16 + lr, nb2 = 2 * 16 + lr, nb3 = 3 * 16 + lr;
  const unsigned swB = (unsigned)((lr & 7) << 4);
  const unsigned offB0 = (unsigned)(nb0 * 512 + lg * 16);
  const unsigned offB1 = (unsigned)(nb1 * 512 + lg * 16);
  const unsigned offB2 = (unsigned)(nb2 * 512 + lg * 16);
  const unsigned offB3 = (unsigned)(nb3 * 512 + lg * 16);

#pragma unroll
  for (int s = 0; s < 8; ++s) {
    const unsigned ks = (unsigned)(s * 64);
    short8 af = *(const short8*)((const char*)A_l + ((offA + ks) ^ swA));
    short8 b0 = *(const short8*)((const char*)B_l + ((offB0 + ks) ^ swB));
    short8 b1 = *(const short8*)((const char*)B_l + ((offB1 + ks) ^ swB));
    short8 b2 = *(const short8*)((const char*)B_l + ((offB2 + ks) ^ swB));
    short8 b3 = *(const short8*)((const char*)B_l + ((offB3 + ks) ^ swB));
    acc0 = __builtin_amdgcn_mfma_f32_16x16x32_bf16(af, b0, acc0, 0, 0, 0);
    acc1 = __builtin_amdgcn_mfma_f32_16x16x32_bf16(af, b1, acc1, 0, 0, 0);
    acc2 = __builtin_amdgcn_mfma_f32_16x16x32_bf16(af, b2, acc2, 0, 0, 0);
    acc3 = __builtin_amdgcn_mfma_f32_16x16x32_bf16(af, b3, acc3, 0, 0, 0);
  }

  // --- epilogue: D col=lane&15, row=lg*4+r (HW-verified m89/m91) ---
  {
    float* pb = partials +
        (((size_t)kp * 1024 + c * 256 + row0 + w * 16 + lg * 4) * 256) +
        col0 + lr;
#pragma unroll
    for (int r = 0; r < 4; ++r) {
      pb[r * 256 + 0]  = acc0[r];
      pb[r * 256 + 16] = acc1[r];
      pb[r * 256 + 32] = acc2[r];
      pb[r * 256 + 48] = acc3[r];
    }
  }
}

// grid = 256 blocks; thread = one pixel; 32 coalesced dword loads.
__global__ __launch_bounds__(256) void gs_finalize(
    const float* __restrict__ partials, float* __restrict__ out) {
  int px = blockIdx.x * 256 + threadIdx.x;
  int row = px >> 8, col = px & 255;
  float s0 = 0.f, s1 = 0.f, s2 = 0.f, s3 = 0.f;
#pragma unroll
  for (int kp = 0; kp < KSPLIT; ++kp) {
    const float* base = partials + (((size_t)kp * 4) * 256 + row) * 256 + col;
    s0 += base[0 * 65536];
    s1 += base[1 * 65536];
    s2 += base[2 * 65536];
    s3 += base[3 * 65536];
  }
  float inv = 1.0f / fmaxf(s3, 1e-5f);
  out[0 * PIX + px] = fminf(fmaxf(s0 * inv, 0.0f), 1.0f);
  out[1 * PIX + px] = fminf(fmaxf(s1 * inv, 0.0f), 1.0f);
  out[2 * PIX + px] = fminf(fmaxf(s2 * inv, 0.0f), 1.0f);
}

extern "C" void kernel_launch(void* const* d_in, const int* in_sizes, int n_in,
                              void* d_out, int out_size, void* d_ws, size_t ws_size,
                              hipStream_t stream) {
  const float* means = (const float*)d_in[0];
  // d_in[1] = quats (unused by reference)
  const float* scales = (const float*)d_in[2];
  const float* opac = (const float*)d_in[3];
  const float* colors = (const float*)d_in[4];
  float* out = (float*)d_out;

  // ws: partials [KSPLIT][1024][256] fp32 = 8 MB
  float* partials = (float*)d_ws;

  // MEASUREMENT: launch twice (idempotent, identical output).
  // dTotal vs R16 = dur(gs_mfma) + ~1us launch gap.
  gs_mfma<<<dim3(16, 4, KSPLIT), 256, 0, stream>>>(
      means, scales, opac, colors, partials);
  gs_mfma<<<dim3(16, 4, KSPLIT), 256, 0, stream>>>(
      means, scales, opac, colors, partials);
  gs_finalize<<<256, 256, 0, stream>>>(partials, out);
}

// Round 18
// 18.958 us; speedup vs baseline: 1.4728x; 1.4728x over previous
//
#include <hip/hip_runtime.h>

// GSplat renderer as a bf16 MFMA GEMM — v2 (R17 measured gs_mfma ~8.5us).
// Changes vs R16: KCH 256->128 with a 2-chunk loop per block (same total
// work), LDS 68->36 KB => 4 blocks/CU (was 2) for cross-block phase overlap;
// single params phase (both chunks at once) removes one sync'd phase.
// M=1024 (4c x 256 rows), N=256, K=2048; grid (16,4,8)=512 blocks.
// Partials [8][1024][256] fp32 = 8 MB; finalize 256 blocks.

constexpr int PIX = 65536;
constexpr int KB = 256;      // gaussians per block (2 chunks of 128)
constexpr int KCH = 128;     // per staging chunk
constexpr int KSPLIT = 8;
constexpr int MT = 64;
constexpr int NT = 64;
constexpr float COORD_STEP = 2.0f / 255.0f;

typedef __attribute__((ext_vector_type(8))) short short8;
typedef __attribute__((ext_vector_type(4))) float f32x4;

__device__ __forceinline__ unsigned cvt_pk_bf16(float lo, float hi) {
  unsigned r;
  asm("v_cvt_pk_bf16_f32 %0, %1, %2" : "=v"(r) : "v"(lo), "v"(hi));
  return r;
}

__global__ __launch_bounds__(256) void gs_mfma(
    const float* __restrict__ means, const float* __restrict__ scales,
    const float* __restrict__ opac, const float* __restrict__ colors,
    float* __restrict__ partials) {
  __shared__ unsigned short A_l[MT * KCH];  // bf16 bits, swizzled (16 KB)
  __shared__ unsigned short B_l[NT * KCH];  // bf16 bits, swizzled (16 KB)
  __shared__ float pxL[KB], pyL[KB], kKL[KB], colL[KB];  // 4 KB

  const int t = threadIdx.x;
  const int mt = blockIdx.x;          // 0..15: c = mt>>2, rowband (mt&3)*64
  const int nt = blockIdx.y;          // 0..3
  const int kp = blockIdx.z;          // 0..7
  const int c = mt >> 2;
  const int row0 = (mt & 3) * MT;
  const int col0 = nt * NT;

  // --- params for BOTH chunks (1 gaussian per thread, once) ---
  {
    int n = kp * KB + t;
    float mx = means[3 * n], my = means[3 * n + 1], mz = means[3 * n + 2];
    float scl = fmaxf((scales[3 * n] + scales[3 * n + 1] + scales[3 * n + 2]) * (1.0f / 3.0f), 1e-4f);
    float op = opac[n];
    float rzs = 1.0f / (fabsf(mz) + 1.0f);
    float sigma = fminf(fmaxf(scl * rzs, 0.02f), 0.5f);
    float inv_s = 1.0f / sigma;
    pxL[t] = tanhf(mx * rzs);
    pyL[t] = tanhf(my * rzs);
    kKL[t] = -0.72134752044f * inv_s * inv_s;  // -0.5/ln2 * inv_s^2
    colL[t] = (c < 3) ? op * colors[3 * n + c] : op;
  }

  // MFMA lane mapping (constant across chunks)
  const int w = t >> 6;
  const int lr = t & 15;
  const int lg = (t >> 4) & 3;
  const int ra = w * 16 + lr;
  const unsigned offA = (unsigned)(ra * 256 + lg * 16);
  const unsigned swA = (unsigned)((ra & 7) << 4);
  const unsigned swB = (unsigned)((lr & 7) << 4);
  const unsigned offB0 = (unsigned)((0 * 16 + lr) * 256 + lg * 16);
  const unsigned offB1 = (unsigned)((1 * 16 + lr) * 256 + lg * 16);
  const unsigned offB2 = (unsigned)((2 * 16 + lr) * 256 + lg * 16);
  const unsigned offB3 = (unsigned)((3 * 16 + lr) * 256 + lg * 16);

  f32x4 acc0 = {0.f, 0.f, 0.f, 0.f};
  f32x4 acc1 = acc0, acc2 = acc0, acc3 = acc0;

  // staging thread mapping
  const int kq = (t & 31) << 2;       // 4 gaussians (local k)
  const int mq = (t >> 5) << 3;       // 8 rows/cols
  const int kbyte = (t & 31) << 3;

  for (int cc = 0; cc < 2; ++cc) {
    __syncthreads();   // params ready (cc=0) / prior MFMA reads done (cc=1)

    // --- stage A (ey*col) and Bt (ex), bf16, swizzled ---
    {
      const int kk = cc * KCH + kq;
      float py0 = pyL[kk + 0], py1 = pyL[kk + 1], py2 = pyL[kk + 2], py3 = pyL[kk + 3];
      float px0 = pxL[kk + 0], px1 = pxL[kk + 1], px2 = pxL[kk + 2], px3 = pxL[kk + 3];
      float K0 = kKL[kk + 0], K1 = kKL[kk + 1], K2 = kKL[kk + 2], K3 = kKL[kk + 3];
      float c0 = colL[kk + 0], c1 = colL[kk + 1], c2 = colL[kk + 2], c3 = colL[kk + 3];
#pragma unroll 4
      for (int j = 0; j < 8; ++j) {
        int m = mq + j;
        float cr = -1.0f + COORD_STEP * (float)(row0 + m);
        float d0 = cr - py0, d1 = cr - py1, d2 = cr - py2, d3 = cr - py3;
        float e0 = exp2f(K0 * d0 * d0) * c0;
        float e1 = exp2f(K1 * d1 * d1) * c1;
        float e2 = exp2f(K2 * d2 * d2) * c2;
        float e3 = exp2f(K3 * d3 * d3) * c3;
        uint2 pa;
        pa.x = cvt_pk_bf16(e0, e1);
        pa.y = cvt_pk_bf16(e2, e3);
        *(uint2*)((char*)A_l + ((m * 256 + kbyte) ^ ((m & 7) << 4))) = pa;
        float ccoord = -1.0f + COORD_STEP * (float)(col0 + m);
        float f0 = ccoord - px0, f1 = ccoord - px1, f2 = ccoord - px2, f3 = ccoord - px3;
        float g0 = exp2f(K0 * f0 * f0);
        float g1 = exp2f(K1 * f1 * f1);
        float g2 = exp2f(K2 * f2 * f2);
        float g3 = exp2f(K3 * f3 * f3);
        uint2 pb;
        pb.x = cvt_pk_bf16(g0, g1);
        pb.y = cvt_pk_bf16(g2, g3);
        *(uint2*)((char*)B_l + ((m * 256 + kbyte) ^ ((m & 7) << 4))) = pb;
      }
    }
    __syncthreads();

    // --- MFMA: 4 s-steps per chunk ---
#pragma unroll
    for (int s = 0; s < 4; ++s) {
      const unsigned ks = (unsigned)(s * 64);
      short8 af = *(const short8*)((const char*)A_l + ((offA + ks) ^ swA));
      short8 b0 = *(const short8*)((const char*)B_l + ((offB0 + ks) ^ swB));
      short8 b1 = *(const short8*)((const char*)B_l + ((offB1 + ks) ^ swB));
      short8 b2 = *(const short8*)((const char*)B_l + ((offB2 + ks) ^ swB));
      short8 b3 = *(const short8*)((const char*)B_l + ((offB3 + ks) ^ swB));
      acc0 = __builtin_amdgcn_mfma_f32_16x16x32_bf16(af, b0, acc0, 0, 0, 0);
      acc1 = __builtin_amdgcn_mfma_f32_16x16x32_bf16(af, b1, acc1, 0, 0, 0);
      acc2 = __builtin_amdgcn_mfma_f32_16x16x32_bf16(af, b2, acc2, 0, 0, 0);
      acc3 = __builtin_amdgcn_mfma_f32_16x16x32_bf16(af, b3, acc3, 0, 0, 0);
    }
  }

  // --- epilogue: D col=lane&15, row=lg*4+r (HW-verified m89/m91) ---
  {
    float* pb = partials +
        (((size_t)kp * 1024 + c * 256 + row0 + w * 16 + lg * 4) * 256) +
        col0 + lr;
#pragma unroll
    for (int r = 0; r < 4; ++r) {
      pb[r * 256 + 0]  = acc0[r];
      pb[r * 256 + 16] = acc1[r];
      pb[r * 256 + 32] = acc2[r];
      pb[r * 256 + 48] = acc3[r];
    }
  }
}

// grid = 256 blocks; thread = one pixel; 32 coalesced dword loads.
__global__ __launch_bounds__(256) void gs_finalize(
    const float* __restrict__ partials, float* __restrict__ out) {
  int px = blockIdx.x * 256 + threadIdx.x;
  int row = px >> 8, col = px & 255;
  float s0 = 0.f, s1 = 0.f, s2 = 0.f, s3 = 0.f;
#pragma unroll
  for (int kp = 0; kp < KSPLIT; ++kp) {
    const float* base = partials + (((size_t)kp * 4) * 256 + row) * 256 + col;
    s0 += base[0 * 65536];
    s1 += base[1 * 65536];
    s2 += base[2 * 65536];
    s3 += base[3 * 65536];
  }
  float inv = 1.0f / fmaxf(s3, 1e-5f);
  out[0 * PIX + px] = fminf(fmaxf(s0 * inv, 0.0f), 1.0f);
  out[1 * PIX + px] = fminf(fmaxf(s1 * inv, 0.0f), 1.0f);
  out[2 * PIX + px] = fminf(fmaxf(s2 * inv, 0.0f), 1.0f);
}

extern "C" void kernel_launch(void* const* d_in, const int* in_sizes, int n_in,
                              void* d_out, int out_size, void* d_ws, size_t ws_size,
                              hipStream_t stream) {
  const float* means = (const float*)d_in[0];
  // d_in[1] = quats (unused by reference)
  const float* scales = (const float*)d_in[2];
  const float* opac = (const float*)d_in[3];
  const float* colors = (const float*)d_in[4];
  float* out = (float*)d_out;

  // ws: partials [KSPLIT][1024][256] fp32 = 8 MB
  float* partials = (float*)d_ws;

  gs_mfma<<<dim3(16, 4, KSPLIT), 256, 0, stream>>>(
      means, scales, opac, colors, partials);
  gs_finalize<<<256, 256, 0, stream>>>(partials, out);
}